// Round 1
// baseline (244.976 us; speedup 1.0000x reference)
//
#include <hip/hip_runtime.h>

// Problem constants (fixed by the reference module)
#define K_   64
#define C_   64
#define W_   128
#define P_   4
#define B_   16
#define W2_  (W_ + 2*P_)        // 136
#define OUTSP (W2_*W2_)         // 18496 elements per (k,c) plane
#define CWW  (C_*W_*W_)         // 1048576 — stride of one cube face row (k index)

// ---------------------------------------------------------------------------
// Kernel 1: interior copy  cube[k,c,r,col] -> out[k,c,r+P, col+P]
// float4 vectorized: 32 float4 per row of 128 floats.
// dst element offset = kc*18496 + (r+4)*136 + 4  ->  multiple of 4 -> aligned.
// ---------------------------------------------------------------------------
__global__ void interior_copy_kernel(const float4* __restrict__ cube4,
                                     float* __restrict__ out) {
    const int n4 = K_ * C_ * W_ * (W_ / 4);   // 4,194,304 float4s
    for (int t = blockIdx.x * blockDim.x + threadIdx.x; t < n4;
         t += gridDim.x * blockDim.x) {
        int q  = t & 31;          // float4 index within row
        int R  = t >> 5;          // global row over (k*c*W)
        int r  = R & (W_ - 1);
        int kc = R >> 7;          // W_=128 rows per plane
        float4 v = cube4[t];
        float4* dst = reinterpret_cast<float4*>(
            out + (size_t)kc * OUTSP + (size_t)(r + P_) * W2_ + P_) + q;
        *dst = v;
    }
}

// ---------------------------------------------------------------------------
// Halo kernels: build inv[] (global face id -> cube row, -1 absent) in LDS
// per block, then gather.
// ---------------------------------------------------------------------------
__global__ void pad_tb_kernel(const float* __restrict__ flat_cube,
                              const int* __restrict__ to_process,
                              const int* __restrict__ pixel_idx_tb,
                              const int* __restrict__ face_idx_tb,
                              float* __restrict__ out) {
    __shared__ int inv[6 * B_];   // 96
    __shared__ int tp[K_];        // 64
    const int tid = threadIdx.x;
    if (tid < 6 * B_) inv[tid] = -1;
    if (tid < K_)     tp[tid]  = to_process[tid];
    __syncthreads();
    if (tid < K_)     inv[tp[tid]] = tid;
    __syncthreads();

    const int NT = K_ * C_ * (2 * P_) * W2_;   // 4,456,448
    for (int t = blockIdx.x * blockDim.x + tid; t < NT;
         t += gridDim.x * blockDim.x) {
        int col  = t % W2_;
        int rest = t / W2_;
        int rr   = rest % (2 * P_);
        rest    /= (2 * P_);
        int cc   = rest % C_;
        int kk   = rest / C_;

        int g  = tp[kk];
        int b  = g / 6;
        int fb = g - 6 * b;
        int nbr = face_idx_tb[(fb * 2 * P_ + rr) * W2_ + col] + 6 * b;
        int f   = inv[nbr];
        int px  = pixel_idx_tb[((fb * C_ + cc) * 2 * P_ + rr) * W2_ + col];
        float v = 0.0f;
        if (f >= 0) v = flat_cube[(size_t)f * CWW + px];

        int outr = (rr < P_) ? rr : (W_ + rr);   // top rows 0..3, bottom 132..135
        out[(size_t)(kk * C_ + cc) * OUTSP + (size_t)outr * W2_ + col] = v;
    }
}

__global__ void pad_lr_kernel(const float* __restrict__ flat_cube,
                              const int* __restrict__ to_process,
                              const int* __restrict__ pixel_idx_lr,
                              const int* __restrict__ face_idx_lr,
                              float* __restrict__ out) {
    __shared__ int inv[6 * B_];
    __shared__ int tp[K_];
    const int tid = threadIdx.x;
    if (tid < 6 * B_) inv[tid] = -1;
    if (tid < K_)     tp[tid]  = to_process[tid];
    __syncthreads();
    if (tid < K_)     inv[tp[tid]] = tid;
    __syncthreads();

    const int NT = K_ * C_ * W_ * (2 * P_);   // 4,194,304
    for (int t = blockIdx.x * blockDim.x + tid; t < NT;
         t += gridDim.x * blockDim.x) {
        int j    = t % (2 * P_);
        int rest = t / (2 * P_);
        int r    = rest % W_;
        rest    /= W_;
        int cc   = rest % C_;
        int kk   = rest / C_;

        int g  = tp[kk];
        int b  = g / 6;
        int fb = g - 6 * b;
        int nbr = face_idx_lr[(fb * W_ + r) * 2 * P_ + j] + 6 * b;
        int f   = inv[nbr];
        int px  = pixel_idx_lr[((fb * C_ + cc) * W_ + r) * 2 * P_ + j];
        float v = 0.0f;
        if (f >= 0) v = flat_cube[(size_t)f * CWW + px];

        int outc = (j < P_) ? j : (W_ + j);      // left cols 0..3, right 132..135
        out[(size_t)(kk * C_ + cc) * OUTSP + (size_t)(r + P_) * W2_ + outc] = v;
    }
}

extern "C" void kernel_launch(void* const* d_in, const int* in_sizes, int n_in,
                              void* d_out, int out_size, void* d_ws, size_t ws_size,
                              hipStream_t stream) {
    const float* cube         = (const float*)d_in[0];
    const int*   to_process   = (const int*)d_in[1];
    // d_in[2] = batch_size (scalar, fixed = 16 by the reference module)
    const int*   pixel_idx_tb = (const int*)d_in[3];
    const int*   pixel_idx_lr = (const int*)d_in[4];
    const int*   face_idx_tb  = (const int*)d_in[5];
    const int*   face_idx_lr  = (const int*)d_in[6];
    float*       out          = (float*)d_out;

    // Interior: 4,194,304 float4s. Grid-stride, ~2 float4/thread.
    interior_copy_kernel<<<4096, 256, 0, stream>>>(
        (const float4*)cube, out);

    // Halos (independent of interior; same stream serialization is fine).
    pad_tb_kernel<<<2048, 256, 0, stream>>>(
        cube, to_process, pixel_idx_tb, face_idx_tb, out);
    pad_lr_kernel<<<2048, 256, 0, stream>>>(
        cube, to_process, pixel_idx_lr, face_idx_lr, out);
}

// Round 5
// 223.289 us; speedup vs baseline: 1.0971x; 1.0971x over previous
//
#include <hip/hip_runtime.h>

// Problem constants (fixed by the reference module)
#define K_   64
#define C_   64
#define W_   128
#define P_   4
#define B_   16
#define W2_  136                 // W + 2*PAD
#define OUTSP 18496              // W2*W2 elements per (k,c) plane
#define CWW  1048576             // C*W*W — cube stride per face (k index)

// Work decomposition in 4-element "quads".
// N_INT = K*C*W*(W/4) = 64*64*128*32 = 16,777,216
#define N_INT 16777216
#define N_TB  1114112            // K*C*(2P)*(W2/4) = 64*64*8*34
#define N_LR  1048576            // K*C*W*2 (left quad, right quad)
#define N_TOT (N_INT + N_TB + N_LR)   // 18,939,904

// clang-native vectors (HIP_vector_type is rejected by nontemporal builtins)
typedef int   int4n   __attribute__((ext_vector_type(4)));
typedef float float4n __attribute__((ext_vector_type(4)));

__global__ void fused_pad_kernel(const float* __restrict__ cube,
                                 const int* __restrict__ to_process,
                                 const int* __restrict__ px_tb,
                                 const int* __restrict__ px_lr,
                                 const int* __restrict__ fi_tb,
                                 const int* __restrict__ fi_lr,
                                 float* __restrict__ out) {
    __shared__ int inv[6 * B_];   // global face id -> cube row, -1 absent
    __shared__ int tp[K_];
    const int tid = threadIdx.x;
    if (tid < 6 * B_) inv[tid] = -1;
    if (tid < K_)     tp[tid]  = to_process[tid];
    __syncthreads();
    if (tid < K_)     inv[tp[tid]] = tid;
    __syncthreads();

    const int stride = gridDim.x * blockDim.x;
    for (int t = blockIdx.x * blockDim.x + tid; t < N_TOT; t += stride) {
        if (t < N_INT) {
            // ---- interior copy: cube[k,c,r,:] -> out[k,c,r+4,4:132] ----
            int q  = t & 31;           // float4 within row (32 per row)
            int R  = t >> 5;           // row over k*c*W
            int r  = R & (W_ - 1);
            int kc = R >> 7;
            float4n v = reinterpret_cast<const float4n*>(cube)[t];
            float4n* dst = reinterpret_cast<float4n*>(
                out + (size_t)kc * OUTSP + (size_t)(r + P_) * W2_ + P_) + q;
            __builtin_nontemporal_store(v, dst);
        } else if (t < N_INT + N_TB) {
            // ---- top/bottom halo: 4 cols per thread ----
            int u    = t - N_INT;
            int col4 = u % 34;
            int rest = u / 34;
            int rr   = rest & 7;  rest >>= 3;
            int cc   = rest & 63;
            int kk   = rest >> 6;

            int g  = tp[kk];
            int b  = g / 6;
            int fb = g - 6 * b;
            int4n fiv = *reinterpret_cast<const int4n*>(
                fi_tb + (fb * 2 * P_ + rr) * W2_ + col4 * 4);
            int4n pxv = *reinterpret_cast<const int4n*>(
                px_tb + (((fb * C_ + cc) * 2 * P_) + rr) * W2_ + col4 * 4);

            float4n v;
            int f0 = inv[fiv.x + 6 * b];
            int f1 = inv[fiv.y + 6 * b];
            int f2 = inv[fiv.z + 6 * b];
            int f3 = inv[fiv.w + 6 * b];
            v.x = (f0 >= 0) ? cube[(size_t)f0 * CWW + pxv.x] : 0.0f;
            v.y = (f1 >= 0) ? cube[(size_t)f1 * CWW + pxv.y] : 0.0f;
            v.z = (f2 >= 0) ? cube[(size_t)f2 * CWW + pxv.z] : 0.0f;
            v.w = (f3 >= 0) ? cube[(size_t)f3 * CWW + pxv.w] : 0.0f;

            int outr = (rr < P_) ? rr : (W_ + rr);   // rows 0..3 / 132..135
            float4n* dst = reinterpret_cast<float4n*>(
                out + (size_t)(kk * C_ + cc) * OUTSP + (size_t)outr * W2_ + col4 * 4);
            __builtin_nontemporal_store(v, dst);
        } else {
            // ---- left/right halo: 4 cols (one side) per thread ----
            int u  = t - N_INT - N_TB;
            int q  = u & 1;                 // 0 = left, 1 = right
            int r  = (u >> 1) & (W_ - 1);
            int cc = (u >> 8) & 63;
            int kk = u >> 14;

            int g  = tp[kk];
            int b  = g / 6;
            int fb = g - 6 * b;
            int4n fiv = *reinterpret_cast<const int4n*>(
                fi_lr + (fb * W_ + r) * 2 * P_ + q * 4);
            int4n pxv = *reinterpret_cast<const int4n*>(
                px_lr + ((fb * C_ + cc) * W_ + r) * 2 * P_ + q * 4);

            float4n v;
            int f0 = inv[fiv.x + 6 * b];
            int f1 = inv[fiv.y + 6 * b];
            int f2 = inv[fiv.z + 6 * b];
            int f3 = inv[fiv.w + 6 * b];
            v.x = (f0 >= 0) ? cube[(size_t)f0 * CWW + pxv.x] : 0.0f;
            v.y = (f1 >= 0) ? cube[(size_t)f1 * CWW + pxv.y] : 0.0f;
            v.z = (f2 >= 0) ? cube[(size_t)f2 * CWW + pxv.z] : 0.0f;
            v.w = (f3 >= 0) ? cube[(size_t)f3 * CWW + pxv.w] : 0.0f;

            int outc = q ? (W_ + P_) : 0;   // col 132 or 0
            float4n* dst = reinterpret_cast<float4n*>(
                out + (size_t)(kk * C_ + cc) * OUTSP + (size_t)(r + P_) * W2_ + outc);
            __builtin_nontemporal_store(v, dst);
        }
    }
}

extern "C" void kernel_launch(void* const* d_in, const int* in_sizes, int n_in,
                              void* d_out, int out_size, void* d_ws, size_t ws_size,
                              hipStream_t stream) {
    const float* cube         = (const float*)d_in[0];
    const int*   to_process   = (const int*)d_in[1];
    // d_in[2] = batch_size (scalar, fixed = 16)
    const int*   pixel_idx_tb = (const int*)d_in[3];
    const int*   pixel_idx_lr = (const int*)d_in[4];
    const int*   face_idx_tb  = (const int*)d_in[5];
    const int*   face_idx_lr  = (const int*)d_in[6];
    float*       out          = (float*)d_out;

    // 2048 blocks x 256 threads = 524,288 lanes, ~36 quads each.
    fused_pad_kernel<<<2048, 256, 0, stream>>>(
        cube, to_process, pixel_idx_tb, pixel_idx_lr,
        face_idx_tb, face_idx_lr, out);
}

// Round 6
// 217.039 us; speedup vs baseline: 1.1287x; 1.0288x over previous
//
#include <hip/hip_runtime.h>

// Problem constants (fixed by the reference module)
#define K_   64
#define C_   64
#define W_   128
#define P_   4
#define B_   16
#define W2_  136                 // W + 2*PAD
#define OUTSP 18496              // W2*W2 elements per (k,c) plane
#define CWW  1048576             // C*W*W — cube stride per face (k index)

// Work in 4-element "quads", grouped into 64-quad wave units.
// Interior: K*C*W*(W/4) = 16,777,216 quads = 262,144 units
// TB halo : K*C*(2P)*(W2/4) = 1,114,112 quads
// LR halo : K*C*W*2         = 1,048,576 quads
// Halo total = 2,162,688 quads = 33,792 units.
// Unit mapping: U -> (g = U/9, r = U%9); r<8 -> interior unit g*8+r,
// r==8 -> halo unit g. 8:1 interleave spreads gathers through the stream.
#define N_INT 16777216
#define N_TB  1114112
#define N_HALO_UNITS 33792
#define N_UNITS (N_HALO_UNITS * 9)          // 304,128
#define N_WID   (N_UNITS * 64)              // 19,464,192 thread-iterations

// clang-native vectors (HIP_vector_type is rejected by nontemporal builtins)
typedef int   int4n   __attribute__((ext_vector_type(4)));
typedef float float4n __attribute__((ext_vector_type(4)));

__global__ void fused_pad_kernel(const float* __restrict__ cube,
                                 const int* __restrict__ to_process,
                                 const int* __restrict__ px_tb,
                                 const int* __restrict__ px_lr,
                                 const int* __restrict__ fi_tb,
                                 const int* __restrict__ fi_lr,
                                 float* __restrict__ out) {
    __shared__ int inv[6 * B_];   // global face id -> cube row, -1 absent
    __shared__ int tp[K_];
    const int tid = threadIdx.x;
    if (tid < 6 * B_) inv[tid] = -1;
    if (tid < K_)     tp[tid]  = to_process[tid];
    __syncthreads();
    if (tid < K_)     inv[tp[tid]] = tid;
    __syncthreads();

    const int stride = gridDim.x * blockDim.x;
    for (int t = blockIdx.x * blockDim.x + tid; t < N_WID; t += stride) {
        int U = t >> 6;            // wave unit index (uniform across the wave)
        int l = t & 63;            // lane within unit
        int g = U / 9;
        int r = U - 9 * g;

        if (r < 8) {
            // ---- interior copy unit: quad id = (g*8+r)*64 + l ----
            int id = ((g << 3) + r) * 64 + l;
            if (id < N_INT) {
                int q  = id & 31;          // float4 within row (32 per row)
                int R  = id >> 5;          // row over k*c*W
                int rr = R & (W_ - 1);
                int kc = R >> 7;
                float4n v = reinterpret_cast<const float4n*>(cube)[id];
                float4n* dst = reinterpret_cast<float4n*>(
                    out + (size_t)kc * OUTSP + (size_t)(rr + P_) * W2_ + P_) + q;
                __builtin_nontemporal_store(v, dst);
            }
        } else {
            // ---- halo unit: quad id = g*64 + l  (always valid) ----
            int id = (g << 6) + l;
            if (id < N_TB) {
                // top/bottom halo: 4 cols per thread
                int col4 = id % 34;
                int rest = id / 34;
                int rr   = rest & 7;  rest >>= 3;
                int cc   = rest & 63;
                int kk   = rest >> 6;

                int gf = tp[kk];
                int b  = gf / 6;
                int fb = gf - 6 * b;
                int4n fiv = *reinterpret_cast<const int4n*>(
                    fi_tb + (fb * 2 * P_ + rr) * W2_ + col4 * 4);
                int4n pxv = *reinterpret_cast<const int4n*>(
                    px_tb + (((fb * C_ + cc) * 2 * P_) + rr) * W2_ + col4 * 4);

                float4n v;
                int f0 = inv[fiv.x + 6 * b];
                int f1 = inv[fiv.y + 6 * b];
                int f2 = inv[fiv.z + 6 * b];
                int f3 = inv[fiv.w + 6 * b];
                v.x = (f0 >= 0) ? cube[(size_t)f0 * CWW + pxv.x] : 0.0f;
                v.y = (f1 >= 0) ? cube[(size_t)f1 * CWW + pxv.y] : 0.0f;
                v.z = (f2 >= 0) ? cube[(size_t)f2 * CWW + pxv.z] : 0.0f;
                v.w = (f3 >= 0) ? cube[(size_t)f3 * CWW + pxv.w] : 0.0f;

                int outr = (rr < P_) ? rr : (W_ + rr);   // rows 0..3 / 132..135
                float4n* dst = reinterpret_cast<float4n*>(
                    out + (size_t)(kk * C_ + cc) * OUTSP + (size_t)outr * W2_ + col4 * 4);
                __builtin_nontemporal_store(v, dst);
            } else {
                // left/right halo: 4 cols (one side) per thread
                int u  = id - N_TB;
                int q  = u & 1;                 // 0 = left, 1 = right
                int rr = (u >> 1) & (W_ - 1);
                int cc = (u >> 8) & 63;
                int kk = u >> 14;

                int gf = tp[kk];
                int b  = gf / 6;
                int fb = gf - 6 * b;
                int4n fiv = *reinterpret_cast<const int4n*>(
                    fi_lr + (fb * W_ + rr) * 2 * P_ + q * 4);
                int4n pxv = *reinterpret_cast<const int4n*>(
                    px_lr + ((fb * C_ + cc) * W_ + rr) * 2 * P_ + q * 4);

                float4n v;
                int f0 = inv[fiv.x + 6 * b];
                int f1 = inv[fiv.y + 6 * b];
                int f2 = inv[fiv.z + 6 * b];
                int f3 = inv[fiv.w + 6 * b];
                v.x = (f0 >= 0) ? cube[(size_t)f0 * CWW + pxv.x] : 0.0f;
                v.y = (f1 >= 0) ? cube[(size_t)f1 * CWW + pxv.y] : 0.0f;
                v.z = (f2 >= 0) ? cube[(size_t)f2 * CWW + pxv.z] : 0.0f;
                v.w = (f3 >= 0) ? cube[(size_t)f3 * CWW + pxv.w] : 0.0f;

                int outc = q ? (W_ + P_) : 0;   // col 132 or 0
                float4n* dst = reinterpret_cast<float4n*>(
                    out + (size_t)(kk * C_ + cc) * OUTSP + (size_t)(rr + P_) * W2_ + outc);
                __builtin_nontemporal_store(v, dst);
            }
        }
    }
}

extern "C" void kernel_launch(void* const* d_in, const int* in_sizes, int n_in,
                              void* d_out, int out_size, void* d_ws, size_t ws_size,
                              hipStream_t stream) {
    const float* cube         = (const float*)d_in[0];
    const int*   to_process   = (const int*)d_in[1];
    // d_in[2] = batch_size (scalar, fixed = 16)
    const int*   pixel_idx_tb = (const int*)d_in[3];
    const int*   pixel_idx_lr = (const int*)d_in[4];
    const int*   face_idx_tb  = (const int*)d_in[5];
    const int*   face_idx_lr  = (const int*)d_in[6];
    float*       out          = (float*)d_out;

    // 2048 blocks x 256 threads = 524,288 lanes; ~37 units per wave, roles
    // cycle every iteration (8192 units/step, 8192 % 9 = 2) so gathers are
    // issued continuously alongside the streaming copy.
    fused_pad_kernel<<<2048, 256, 0, stream>>>(
        cube, to_process, pixel_idx_tb, pixel_idx_lr,
        face_idx_tb, face_idx_lr, out);
}